// Round 13
// baseline (405.213 us; speedup 1.0000x reference)
//
#include <hip/hip_runtime.h>
#include <hip/hip_bf16.h>
#include <math.h>

// Problem constants
#define SEQ 4096
#define LL  4097           // sequence + CLS
#define HDIM 32
#define FFD 2048
#define NLAYER 6
#define EPSLN 1e-5f
#define NCHUNK 16          // split-K chunks over keys (256 keys each, last 288)
#define KPAD 4128          // keys 0..4096 padded to 129*32
#define QROWS 4352         // 17 blocks * 4 waves * 64 queries
#define RB2 16             // fused FFN kernel row block

#if __has_builtin(__builtin_amdgcn_exp2f)
#define EXP2 __builtin_amdgcn_exp2f
#else
#define EXP2 exp2f
#endif

#define QSCALE 0.7213475204444817f   // 0.5 * log2(e)

typedef short bf16x8 __attribute__((ext_vector_type(8)));
typedef short bf16x4 __attribute__((ext_vector_type(4)));
typedef float f32x4 __attribute__((ext_vector_type(4)));

__device__ __forceinline__ unsigned short f2b(float f) {   // fp32 -> bf16 RNE
  unsigned int b = __float_as_uint(f);
  b += 0x7FFFu + ((b >> 16) & 1u);
  return (unsigned short)(b >> 16);
}

__device__ __forceinline__ float b2f(unsigned short u) {   // bf16 -> fp32
  unsigned int b = ((unsigned int)u) << 16;
  return __uint_as_float(b);
}

__device__ __forceinline__ unsigned int pk_bf16(float a, float b) {
  __hip_bfloat162 h = __float22bfloat162_rn(make_float2(a, b));
  return *(unsigned int*)&h;
}

// K=16 bf16 MFMA for QK^T (head dim 4 -> half the matrix-pipe cost of K=32).
__device__ __forceinline__ f32x4 mfma_qk(bf16x4 a, bf16x4 b, f32x4 c) {
#if __has_builtin(__builtin_amdgcn_mfma_f32_16x16x16bf16_1k)
  return __builtin_amdgcn_mfma_f32_16x16x16bf16_1k(a, b, c, 0, 0, 0);
#else
  bf16x8 a8 = {a[0], a[1], a[2], a[3], 0, 0, 0, 0};
  bf16x8 b8 = {b[0], b[1], b[2], b[3], 0, 0, 0, 0};
  return __builtin_amdgcn_mfma_f32_16x16x32_bf16(a8, b8, c, 0, 0, 0);
#endif
}

// Buffers:
//  Qb  [QROWS][32]  bf16, pre-scaled by QSCALE (pad rows zero).
//  KB4 [8][KPAD][4] bf16 — head h's 4 K dims per key; pad rows zeroed once.
//  VB5 [8][5][KPAD] bf16, rows 0..3 = V dims (permuted key order), row 4 =
//      validity. Key permutation within 32-blocks: pos = ((w&15)<<1) | (w>>4)
//      — so pk(exp(S[k]), exp(S[k+16])) is directly the PV B-frag in-lane.
//  AP [(c*LL+q)*32 + h*4+d] float — split-K numerator partials; a row's 32
//      lanes read ONE contiguous 128B line per chunk.
//  LP [(c*LL+q)*8 + h] float — split-K denominators, one 32B segment/row.
//  X  [LL][32] fp32 — residual stream (updated at LN2 only).

// wave-level qkv projection + bf16 stores. y = this thread's (row,ch) value.
__device__ __forceinline__ void qkv_wave(float y, int row, bool ok, int lane,
    const float* __restrict__ qw, const float* __restrict__ qb,
    unsigned short* __restrict__ Qb, unsigned short* __restrict__ KB4,
    unsigned short* __restrict__ VB5) {
  int ch = lane & 31;
  float xv[32];
#pragma unroll
  for (int k = 0; k < 32; ++k) xv[k] = __shfl(y, (lane & 32) + k, 64);
#pragma unroll
  for (int t3 = 0; t3 < 3; ++t3) {
    int cc = t3 * 32 + ch;
    const float4* wr = (const float4*)(qw + (size_t)cc * 32);
    float acc = qb[cc];
#pragma unroll
    for (int k8 = 0; k8 < 8; ++k8) {
      float4 wv = wr[k8];
      acc = fmaf(xv[4 * k8 + 0], wv.x, acc);
      acc = fmaf(xv[4 * k8 + 1], wv.y, acc);
      acc = fmaf(xv[4 * k8 + 2], wv.z, acc);
      acc = fmaf(xv[4 * k8 + 3], wv.w, acc);
    }
    if (ok) {
      int h = ch >> 2;
      if (t3 == 0) {
        Qb[(size_t)row * 32 + ch] = f2b(QSCALE * acc);
      } else if (t3 == 1) {
        KB4[((size_t)h * KPAD + row) * 4 + (ch & 3)] = f2b(acc);
      } else {
        int w = row & 31;
        int pos = ((w & 15) << 1) | (w >> 4);
        VB5[((size_t)h * 5 + (ch & 3)) * KPAD + (row & ~31) + pos] = f2b(acc);
      }
    }
  }
}

// ---- init: weight cvt + pad zeroing + embed + layer-0 qkv (all disjoint) ---
__global__ __launch_bounds__(256) void k_init(const float* __restrict__ data,
    const float* __restrict__ lin_w, const float* __restrict__ lin_b,
    const float* __restrict__ qkv_w, const float* __restrict__ qkv_b,
    const float* __restrict__ ff1_w, const float* __restrict__ ff2_w,
    float* __restrict__ X, unsigned short* __restrict__ Qb,
    unsigned short* __restrict__ KB4, unsigned short* __restrict__ VB5,
    unsigned short* __restrict__ W1B, unsigned short* __restrict__ W2B) {
  int gid = blockIdx.x * 256 + threadIdx.x;
  int gsz = gridDim.x * 256;
  const int NW = NLAYER * FFD * 32;
  for (int i = gid; i < NW; i += gsz) {
    W1B[i] = f2b(ff1_w[i]);
    W2B[i] = f2b(ff2_w[i]);
  }
  for (int i = gid; i < (QROWS - LL) * 32; i += gsz)
    Qb[(size_t)LL * 32 + i] = 0;                    // query pad rows
  for (int i = gid; i < 8 * (KPAD - LL) * 4; i += gsz) {
    int hh = i / ((KPAD - LL) * 4);
    int rem = i % ((KPAD - LL) * 4);
    KB4[((size_t)hh * KPAD + LL) * 4 + rem] = 0;    // K pad rows
  }
  for (int i = gid; i < 8 * 5 * KPAD; i += gsz) {
    int col = i % KPAD;
    int dd = (i / KPAD) % 5;
    if (dd == 4) {
      int key = (col & ~31) + ((col & 1) << 4) + ((col & 31) >> 1);
      VB5[i] = (key <= 4096) ? 0x3F80 : 0;          // validity row
    } else if (col > 4096) {
      VB5[i] = 0;                                   // pad-key V entries
    }
  }
  // embed + layer-0 qkv: wave items, 2 rows each
  int wave = threadIdx.x >> 6, lane = threadIdx.x & 63;
  int r = lane >> 5, ch = lane & 31;
  unsigned wgid = blockIdx.x * 4 + wave;
  for (unsigned it = wgid; it < 2049; it += gridDim.x * 4) {
    int row = it * 2 + r;
    bool ok = row < LL;
    float val = 0.f;
    if (ok) {
      if (row == 0) {
        val = -1.0f;
      } else {
        int s = row - 1;
        float ts = data[s * 3 + 0];
        float f0 = data[s * 3 + 1];
        float f1 = data[s * 3 + 2];
        float lin = f0 * lin_w[ch * 2 + 0] + f1 * lin_w[ch * 2 + 1] + lin_b[ch];
        lin = fmaxf(lin, 0.0f);
        int tsi = (int)(ts / 100.0f);
        int j = ch >> 1;
        float aj = (float)(2 * j) * (float)(-0.28782313662425575);
        float divj = (float)exp((double)aj);
        float ang = (float)tsi * divj;
        float pe = (ch & 1) ? cosf(ang) : sinf(ang);
        val = lin + pe;
      }
      X[(size_t)row * HDIM + ch] = val;
    }
    qkv_wave(val, row, ok, lane, qkv_w, qkv_b, Qb, KB4, VB5);
  }
}

// ---- attention, swapped-operand MFMA: NO LDS, no transpose (r11 body) ------
__global__ __launch_bounds__(256, 4) void k_attn(
    const unsigned short* __restrict__ Qb, const unsigned short* __restrict__ KB4,
    const unsigned short* __restrict__ VB5, float* __restrict__ LP,
    float4* __restrict__ AP4) {
  int tid = threadIdx.x;
  int wave = tid >> 6, lane = tid & 63;
  int l16 = lane & 15, quad = lane >> 4;
  int h = blockIdx.y, c = blockIdx.z;
  int qs = blockIdx.x * 4 + wave;
  if (qs >= 65) return;                  // wave-uniform exit, no barriers used
  int q0 = qs * 64;
  int kb0 = c * 256;
  int nkb = (c == NCHUNK - 1) ? 9 : 8;

  const unsigned short* KBh = KB4 + (size_t)h * KPAD * 4;
  const unsigned short* VBh = VB5 + (size_t)h * 5 * KPAD;
  const bool kl = (quad == (h & 3));    // carrying quad for K=16 contraction
  const bool vl = (l16 < 5);            // only V rows 0..4 are nonzero
  const int qcol0 = (h >> 2) * 16 + quad * 4;   // Q columns for this quad

  bf16x4 aq[4];                          // Q tiles: B-operand (row = l16 = q)
#pragma unroll
  for (int t = 0; t < 4; ++t)
    aq[t] = *(const bf16x4*)&Qb[(size_t)(q0 + t * 16 + l16) * 32 + qcol0];

  const bf16x4 zb4 = {0, 0, 0, 0};
  const bf16x8 zb8 = {0, 0, 0, 0, 0, 0, 0, 0};
  f32x4 acc0[4], acc1[4];
#pragma unroll
  for (int t = 0; t < 4; ++t) {
    acc0[t] = (f32x4){0.f, 0.f, 0.f, 0.f};
    acc1[t] = (f32x4){0.f, 0.f, 0.f, 0.f};
  }

  auto step = [&](int k0, f32x4* acc) {
    bf16x4 bk0 = kl ? *(const bf16x4*)&KBh[(size_t)(k0 + l16) * 4] : zb4;
    bf16x4 bk1 = kl ? *(const bf16x4*)&KBh[(size_t)(k0 + 16 + l16) * 4] : zb4;
    bf16x8 bv = vl ? *(const bf16x8*)&VBh[(size_t)l16 * KPAD + k0 + quad * 8]
                   : zb8;
    f32x4 z = {0.f, 0.f, 0.f, 0.f};
    unsigned pf[4][4];                   // packed P fragments (bf16x8 each)
#pragma unroll
    for (int t = 0; t < 4; ++t) {
      f32x4 s0 = mfma_qk(bk0, aq[t], z);
      f32x4 s1 = mfma_qk(bk1, aq[t], z);
#pragma unroll
      for (int reg = 0; reg < 4; ++reg)
        pf[t][reg] = pk_bf16(EXP2(s0[reg]), EXP2(s1[reg]));
    }
#pragma unroll
    for (int t = 0; t < 4; ++t) {
      bf16x8 pb = *(const bf16x8*)&pf[t][0];
      acc[t] = __builtin_amdgcn_mfma_f32_16x16x32_bf16(bv, pb, acc[t], 0, 0, 0);
    }
  };

  int kb = 0;
  for (; kb + 2 <= nkb; kb += 2) {
    step(kb0 + kb * 32, acc0);
    step(kb0 + (kb + 1) * 32, acc1);
  }
  if (kb < nkb) step(kb0 + kb * 32, acc0);

  // Output: lane holds O^T rows d=quad*4+reg for q=l16 of each tile.
#pragma unroll
  for (int t = 0; t < 4; ++t) {
    f32x4 a = acc0[t] + acc1[t];
    int q = q0 + t * 16 + l16;
    if (q < LL) {
      if (quad == 0) {
        AP4[((size_t)c * LL + q) * 8 + h] = make_float4(a[0], a[1], a[2], a[3]);
      } else if (quad == 1) {
        LP[((size_t)c * LL + q) * 8 + h] = a[0];
      }
    }
  }
}

// ---- fused per-16-row block: oproj+LN1 -> full FFN -> LN2 -> next qkv ------
// grid (257) x 512 threads (8 waves). Wave w owns the 256-wide f-slice.
__global__ __launch_bounds__(512, 4) void k_ffnF(const float* __restrict__ LP,
    const float* __restrict__ APf, float* __restrict__ X,
    const float* __restrict__ ow, const float* __restrict__ ob,
    const float* __restrict__ g1, const float* __restrict__ b1ln,
    const unsigned short* __restrict__ w1b, const float* __restrict__ fb1,
    const unsigned short* __restrict__ w2b, const float* __restrict__ fb2,
    const float* __restrict__ g2, const float* __restrict__ b2ln,
    const float* __restrict__ qw, const float* __restrict__ qb,
    unsigned short* __restrict__ Qb, unsigned short* __restrict__ KB4,
    unsigned short* __restrict__ VB5) {
  __shared__ unsigned short Xa[RB2][32];      // bf16 LN1 out (GEMM1 A-tile)
  __shared__ float Y1[RB2][32];               // fp32 LN1 out (FFN residual)
  __shared__ unsigned short Fsb[8][16 * 136]; // per-wave transpose buffers
  __shared__ float Pr[8][RB2 * 33];           // per-wave GEMM2 partials
  int tid = threadIdx.x;
  int wave = tid >> 6, lane = tid & 63;
  int l16 = lane & 15, quad = lane >> 4;
  int r = lane >> 5, ch = lane & 31;
  int r0 = blockIdx.x * RB2;

  // Phase A: split-K combine + o-proj + residual + LN1 (2 rows per wave)
  {
    int rl = wave * 2 + r;
    int row = r0 + rl;
    bool ok = row < LL;
    int hh = ch >> 2;
    float L = 0.f, A = 0.f;
    if (ok) {
#pragma unroll
      for (int c = 0; c < NCHUNK; ++c) {
        A += APf[((size_t)c * LL + row) * 32 + ch];
        L += LP[((size_t)c * LL + row) * 8 + hh];
      }
    }
    float os = ok ? A / L : 0.f;
    float acc = 0.f;
    const float4* owr = (const float4*)(ow + (size_t)ch * 32);
#pragma unroll
    for (int k8 = 0; k8 < 8; ++k8) {
      float4 wv = owr[k8];
      acc = fmaf(__shfl(os, (lane & 32) + 4 * k8 + 0, 64), wv.x, acc);
      acc = fmaf(__shfl(os, (lane & 32) + 4 * k8 + 1, 64), wv.y, acc);
      acc = fmaf(__shfl(os, (lane & 32) + 4 * k8 + 2, 64), wv.z, acc);
      acc = fmaf(__shfl(os, (lane & 32) + 4 * k8 + 3, 64), wv.w, acc);
    }
    float val = ok ? (X[(size_t)row * HDIM + ch] + acc + ob[ch]) : 0.f;
    float mean = val;
#pragma unroll
    for (int off = 16; off > 0; off >>= 1) mean += __shfl_xor(mean, off, 32);
    mean *= (1.f / 32.f);
    float d2 = val - mean;
    float var = d2 * d2;
#pragma unroll
    for (int off = 16; off > 0; off >>= 1) var += __shfl_xor(var, off, 32);
    var *= (1.f / 32.f);
    float y = d2 / sqrtf(var + EPSLN) * g1[ch] + b1ln[ch];
    Y1[rl][ch] = y;
    Xa[rl][ch] = ok ? f2b(y) : 0;
  }
  __syncthreads();

  // Phase B: FFN over this wave's 256-wide f-slice (wave-private transpose)
  bf16x8 a1 = *(const bf16x8*)&Xa[l16][quad * 8];
  f32x4 acc2[2] = {{0.f, 0.f, 0.f, 0.f}, {0.f, 0.f, 0.f, 0.f}};
  int fs0 = wave * 256;
#pragma unroll
  for (int sg = 0; sg < 2; ++sg) {
    int f0 = fs0 + sg * 128;
    f32x4 c1[8];
#pragma unroll
    for (int t = 0; t < 8; ++t) {
      bf16x8 b =
          *(const bf16x8*)&w1b[(size_t)(f0 + t * 16 + l16) * 32 + quad * 8];
      f32x4 z = {0.f, 0.f, 0.f, 0.f};
      c1[t] = __builtin_amdgcn_mfma_f32_16x16x32_bf16(a1, b, z, 0, 0, 0);
    }
#pragma unroll
    for (int t = 0; t < 8; ++t) {
      float bb = fb1[f0 + t * 16 + l16];
#pragma unroll
      for (int reg = 0; reg < 4; ++reg) {
        float v = fmaxf(c1[t][reg] + bb, 0.f);
        Fsb[wave][(quad * 4 + reg) * 136 + t * 16 + l16] = f2b(v);
      }
    }
    // Fsb is wave-private; in-order per-wave DS -> no barrier
#pragma unroll
    for (int kt = 0; kt < 4; ++kt) {
      bf16x8 a2 = *(const bf16x8*)&Fsb[wave][l16 * 136 + kt * 32 + quad * 8];
#pragma unroll
      for (int u = 0; u < 2; ++u) {
        bf16x8 b = *(const bf16x8*)&w2b[(size_t)(u * 16 + l16) * FFD + f0 +
                                        kt * 32 + quad * 8];
        acc2[u] =
            __builtin_amdgcn_mfma_f32_16x16x32_bf16(a2, b, acc2[u], 0, 0, 0);
      }
    }
  }
#pragma unroll
  for (int u = 0; u < 2; ++u)
#pragma unroll
    for (int reg = 0; reg < 4; ++reg)
      Pr[wave][(quad * 4 + reg) * 33 + u * 16 + l16] = acc2[u][reg];
  __syncthreads();

  // Phase C: reduce 8 wave partials + residual + LN2 + next layer's qkv
  {
    int rl = wave * 2 + r;
    int row = r0 + rl;
    bool ok = row < LL;
    float s = 0.f;
#pragma unroll
    for (int w = 0; w < 8; ++w) s += Pr[w][rl * 33 + ch];
    float val = ok ? (Y1[rl][ch] + s + fb2[ch]) : 0.f;
    float mean = val;
#pragma unroll
    for (int off = 16; off > 0; off >>= 1) mean += __shfl_xor(mean, off, 32);
    mean *= (1.f / 32.f);
    float d2 = val - mean;
    float var = d2 * d2;
#pragma unroll
    for (int off = 16; off > 0; off >>= 1) var += __shfl_xor(var, off, 32);
    var *= (1.f / 32.f);
    float y = d2 / sqrtf(var + EPSLN) * g2[ch] + b2ln[ch];
    if (ok) X[(size_t)row * HDIM + ch] = y;
    qkv_wave(y, row, ok, lane, qw, qb, Qb, KB4, VB5);
  }
}

// ---- last layer: CLS-only (query 0). One block, 256 threads. ---------------
// attn q=0 (8 heads x 32 lanes, scalar fp32, exp2 semantics identical to the
// MFMA path since Qb is pre-scaled) -> oproj+LN1 row 0 -> FFN row 0 (fp32
// weights, deterministic 8-segment reduce) -> LN2 -> classifier.
__global__ __launch_bounds__(256) void k_last(
    const unsigned short* __restrict__ Qb, const unsigned short* __restrict__ KB4,
    const unsigned short* __restrict__ VB5, const float* __restrict__ X,
    const float* __restrict__ ow, const float* __restrict__ ob,
    const float* __restrict__ g1, const float* __restrict__ b1ln,
    const float* __restrict__ w1, const float* __restrict__ fb1,
    const float* __restrict__ w2, const float* __restrict__ fb2,
    const float* __restrict__ g2, const float* __restrict__ b2ln,
    const float* __restrict__ cw, const float* __restrict__ cb,
    float* __restrict__ out) {
  __shared__ float os_sh[32];
  __shared__ float y1_sh[32];
  __shared__ float f_sh[FFD];
  __shared__ float red[8][32];
  int tid = threadIdx.x;
  int h = tid >> 5, l32 = tid & 31;

  // phase 1: attention for q=0; head h over 32 lanes, keys strided
  float q[4];
#pragma unroll
  for (int d = 0; d < 4; ++d) q[d] = b2f(Qb[h * 4 + d]);   // pre-scaled
  float num[4] = {0.f, 0.f, 0.f, 0.f};
  float den = 0.f;
#pragma unroll 2
  for (int k = l32; k < LL; k += 32) {
    bf16x4 kr = *(const bf16x4*)&KB4[((size_t)h * KPAD + k) * 4];
    float s = 0.f;
#pragma unroll
    for (int d = 0; d < 4; ++d)
      s = fmaf(q[d], b2f((unsigned short)kr[d]), s);
    float p = EXP2(s);
    int w = k & 31;
    int pos = (k & ~31) + (((w & 15) << 1) | (w >> 4));
#pragma unroll
    for (int d = 0; d < 4; ++d)
      num[d] = fmaf(p, b2f(VB5[((size_t)h * 5 + d) * KPAD + pos]), num[d]);
    den += p;
  }
#pragma unroll
  for (int off = 16; off > 0; off >>= 1) {
#pragma unroll
    for (int d = 0; d < 4; ++d) num[d] += __shfl_xor(num[d], off, 32);
    den += __shfl_xor(den, off, 32);
  }
  if (l32 < 4) os_sh[h * 4 + l32] = num[l32] / den;
  __syncthreads();

  // phase 2: oproj + residual + LN1 for row 0 (one wave-half)
  if (tid < 32) {
    int ch = tid;
    float acc = 0.f;
#pragma unroll
    for (int k = 0; k < 32; ++k) acc = fmaf(os_sh[k], ow[ch * 32 + k], acc);
    float val = X[ch] + acc + ob[ch];
    float mean = val;
#pragma unroll
    for (int off = 16; off > 0; off >>= 1) mean += __shfl_xor(mean, off, 32);
    mean *= (1.f / 32.f);
    float d2 = val - mean;
    float var = d2 * d2;
#pragma unroll
    for (int off = 16; off > 0; off >>= 1) var += __shfl_xor(var, off, 32);
    var *= (1.f / 32.f);
    y1_sh[ch] = d2 / sqrtf(var + EPSLN) * g1[ch] + b1ln[ch];
  }
  __syncthreads();

  // phase 3a: f = relu(W1 . y1 + b1), 8 values per thread
  for (int i = tid; i < FFD; i += 256) {
    const float* wr = w1 + (size_t)i * 32;
    float acc = fb1[i];
#pragma unroll
    for (int j = 0; j < 32; ++j) acc = fmaf(y1_sh[j], wr[j], acc);
    f_sh[i] = fmaxf(acc, 0.f);
  }
  __syncthreads();

  // phase 3b: partial GEMV for W2: seg h covers f[h*256 .. +255], ch = l32
  {
    float acc = 0.f;
    const float* wr = w2 + (size_t)l32 * FFD + h * 256;
    const float* fr = &f_sh[h * 256];
#pragma unroll 8
    for (int j = 0; j < 256; ++j) acc = fmaf(fr[j], wr[j], acc);
    red[h][l32] = acc;
  }
  __syncthreads();

  // phase 4: combine + residual + LN2 + classifier
  if (tid < 32) {
    int ch = tid;
    float s = 0.f;
#pragma unroll
    for (int sg = 0; sg < 8; ++sg) s += red[sg][ch];
    float val = y1_sh[ch] + s + fb2[ch];
    float mean = val;
#pragma unroll
    for (int off = 16; off > 0; off >>= 1) mean += __shfl_xor(mean, off, 32);
    mean *= (1.f / 32.f);
    float d2 = val - mean;
    float var = d2 * d2;
#pragma unroll
    for (int off = 16; off > 0; off >>= 1) var += __shfl_xor(var, off, 32);
    var *= (1.f / 32.f);
    float y = d2 / sqrtf(var + EPSLN) * g2[ch] + b2ln[ch];
    float t = y * cw[ch];
#pragma unroll
    for (int off = 16; off > 0; off >>= 1) t += __shfl_xor(t, off, 32);
    if (ch == 0) out[0] = 1.f / (1.f + expf(-(t + cb[0])));
  }
}

extern "C" void kernel_launch(void* const* d_in, const int* in_sizes, int n_in,
                              void* d_out, int out_size, void* d_ws,
                              size_t ws_size, hipStream_t stream) {
  const float* data  = (const float*)d_in[0];
  const float* lin_w = (const float*)d_in[1];
  const float* lin_b = (const float*)d_in[2];
  const float* qkv_w = (const float*)d_in[3];
  const float* qkv_b = (const float*)d_in[4];
  const float* out_w = (const float*)d_in[5];
  const float* out_b = (const float*)d_in[6];
  const float* ln1_g = (const float*)d_in[7];
  const float* ln1_b = (const float*)d_in[8];
  const float* ff1_w = (const float*)d_in[9];
  const float* ff1_b = (const float*)d_in[10];
  const float* ff2_w = (const float*)d_in[11];
  const float* ff2_b = (const float*)d_in[12];
  const float* ln2_g = (const float*)d_in[13];
  const float* ln2_b = (const float*)d_in[14];
  const float* cls_w = (const float*)d_in[15];
  const float* cls_b = (const float*)d_in[16];

  char* wsb = (char*)d_ws;
  float* X = (float*)wsb;                               // LL*32 fp32
  unsigned short* Qb  = (unsigned short*)(X + (size_t)LL * 32);
  unsigned short* KB4 = Qb + (size_t)QROWS * 32;        // 8*KPAD*4
  unsigned short* VB5 = KB4 + (size_t)8 * KPAD * 4;     // 8*5*KPAD
  unsigned short* W1B = VB5 + (size_t)8 * 5 * KPAD;     // NL*FFD*32
  unsigned short* W2B = W1B + (size_t)NLAYER * FFD * 32;
  float4* AP = (float4*)(((size_t)(W2B + (size_t)NLAYER * FFD * 32) + 15) &
                         ~(size_t)15);                  // NCHUNK*LL*8 float4
  float* LP = (float*)(AP + (size_t)NCHUNK * LL * 8);   // NCHUNK*LL*8 floats

  k_init<<<1024, 256, 0, stream>>>(data, lin_w, lin_b, qkv_w, qkv_b,
                                   ff1_w, ff2_w, X, Qb, KB4, VB5, W1B, W2B);
  for (int l = 0; l < NLAYER - 1; ++l) {
    k_attn<<<dim3(17, 8, NCHUNK), 256, 0, stream>>>(Qb, KB4, VB5, LP, AP);
    // ffnF always computes the NEXT layer's qkv (layer l+1; l+1 <= 5)
    const float* qw = qkv_w + (size_t)(l + 1) * 96 * 32;
    const float* qb = qkv_b + (size_t)(l + 1) * 96;
    k_ffnF<<<(LL + RB2 - 1) / RB2, 512, 0, stream>>>(
        LP, (const float*)AP, X,
        out_w + (size_t)l * 32 * 32, out_b + (size_t)l * 32,
        ln1_g + (size_t)l * 32, ln1_b + (size_t)l * 32,
        W1B + (size_t)l * FFD * 32, ff1_b + (size_t)l * FFD,
        W2B + (size_t)l * FFD * 32, ff2_b + (size_t)l * 32,
        ln2_g + (size_t)l * 32, ln2_b + (size_t)l * 32,
        qw, qb, Qb, KB4, VB5);
  }
  // layer 5: only CLS (row 0) is consumed downstream -> one tiny block
  {
    const int l = NLAYER - 1;
    k_last<<<1, 256, 0, stream>>>(
        Qb, KB4, VB5, X,
        out_w + (size_t)l * 32 * 32, out_b + (size_t)l * 32,
        ln1_g + (size_t)l * 32, ln1_b + (size_t)l * 32,
        ff1_w + (size_t)l * FFD * 32, ff1_b + (size_t)l * FFD,
        ff2_w + (size_t)l * 32 * FFD, ff2_b + (size_t)l * 32,
        ln2_g + (size_t)l * 32, ln2_b + (size_t)l * 32,
        cls_w, cls_b, (float*)d_out);
  }
}

// Round 14
// 366.084 us; speedup vs baseline: 1.1069x; 1.1069x over previous
//
#include <hip/hip_runtime.h>
#include <hip/hip_bf16.h>
#include <math.h>

// Problem constants
#define SEQ 4096
#define LL  4097           // sequence + CLS
#define HDIM 32
#define FFD 2048
#define NLAYER 6
#define EPSLN 1e-5f
#define NCHUNK 16          // split-K chunks over keys (256 keys each, last 288)
#define KPAD 4128          // keys 0..4096 padded to 129*32
#define QROWS 4352         // 17 blocks * 4 waves * 64 queries
#define RB2 16             // fused FFN kernel row block
#define LB 32              // last-layer FFN blocks (64-wide f slices)

#if __has_builtin(__builtin_amdgcn_exp2f)
#define EXP2 __builtin_amdgcn_exp2f
#else
#define EXP2 exp2f
#endif

#define QSCALE 0.7213475204444817f   // 0.5 * log2(e)

typedef short bf16x8 __attribute__((ext_vector_type(8)));
typedef short bf16x4 __attribute__((ext_vector_type(4)));
typedef float f32x4 __attribute__((ext_vector_type(4)));

__device__ __forceinline__ unsigned short f2b(float f) {   // fp32 -> bf16 RNE
  unsigned int b = __float_as_uint(f);
  b += 0x7FFFu + ((b >> 16) & 1u);
  return (unsigned short)(b >> 16);
}

__device__ __forceinline__ float b2f(unsigned short u) {   // bf16 -> fp32
  unsigned int b = ((unsigned int)u) << 16;
  return __uint_as_float(b);
}

__device__ __forceinline__ unsigned int pk_bf16(float a, float b) {
  __hip_bfloat162 h = __float22bfloat162_rn(make_float2(a, b));
  return *(unsigned int*)&h;
}

// K=16 bf16 MFMA for QK^T (head dim 4 -> half the matrix-pipe cost of K=32).
__device__ __forceinline__ f32x4 mfma_qk(bf16x4 a, bf16x4 b, f32x4 c) {
#if __has_builtin(__builtin_amdgcn_mfma_f32_16x16x16bf16_1k)
  return __builtin_amdgcn_mfma_f32_16x16x16bf16_1k(a, b, c, 0, 0, 0);
#else
  bf16x8 a8 = {a[0], a[1], a[2], a[3], 0, 0, 0, 0};
  bf16x8 b8 = {b[0], b[1], b[2], b[3], 0, 0, 0, 0};
  return __builtin_amdgcn_mfma_f32_16x16x32_bf16(a8, b8, c, 0, 0, 0);
#endif
}

// Buffers:
//  Qb  [QROWS][32]  bf16, pre-scaled by QSCALE (pad rows zero).
//  KB4 [8][KPAD][4] bf16 — head h's 4 K dims per key; pad rows zeroed once.
//  VB5 [8][5][KPAD] bf16, rows 0..3 = V dims (permuted key order), row 4 =
//      validity. Key permutation within 32-blocks: pos = ((w&15)<<1) | (w>>4)
//      — so pk(exp(S[k]), exp(S[k+16])) is directly the PV B-frag in-lane.
//  AP [(c*LL+q)*32 + h*4+d] float — split-K numerator partials; a row's 32
//      lanes read ONE contiguous 128B line per chunk.
//  LP [(c*LL+q)*8 + h] float — split-K denominators, one 32B segment/row.
//  X  [LL][32] fp32 — residual stream (updated at LN2 only).

// wave-level qkv projection + bf16 stores. y = this thread's (row,ch) value.
__device__ __forceinline__ void qkv_wave(float y, int row, bool ok, int lane,
    const float* __restrict__ qw, const float* __restrict__ qb,
    unsigned short* __restrict__ Qb, unsigned short* __restrict__ KB4,
    unsigned short* __restrict__ VB5) {
  int ch = lane & 31;
  float xv[32];
#pragma unroll
  for (int k = 0; k < 32; ++k) xv[k] = __shfl(y, (lane & 32) + k, 64);
#pragma unroll
  for (int t3 = 0; t3 < 3; ++t3) {
    int cc = t3 * 32 + ch;
    const float4* wr = (const float4*)(qw + (size_t)cc * 32);
    float acc = qb[cc];
#pragma unroll
    for (int k8 = 0; k8 < 8; ++k8) {
      float4 wv = wr[k8];
      acc = fmaf(xv[4 * k8 + 0], wv.x, acc);
      acc = fmaf(xv[4 * k8 + 1], wv.y, acc);
      acc = fmaf(xv[4 * k8 + 2], wv.z, acc);
      acc = fmaf(xv[4 * k8 + 3], wv.w, acc);
    }
    if (ok) {
      int h = ch >> 2;
      if (t3 == 0) {
        Qb[(size_t)row * 32 + ch] = f2b(QSCALE * acc);
      } else if (t3 == 1) {
        KB4[((size_t)h * KPAD + row) * 4 + (ch & 3)] = f2b(acc);
      } else {
        int w = row & 31;
        int pos = ((w & 15) << 1) | (w >> 4);
        VB5[((size_t)h * 5 + (ch & 3)) * KPAD + (row & ~31) + pos] = f2b(acc);
      }
    }
  }
}

// ---- init: weight cvt + pad zeroing + embed + layer-0 qkv (all disjoint) ---
__global__ __launch_bounds__(256) void k_init(const float* __restrict__ data,
    const float* __restrict__ lin_w, const float* __restrict__ lin_b,
    const float* __restrict__ qkv_w, const float* __restrict__ qkv_b,
    const float* __restrict__ ff1_w, const float* __restrict__ ff2_w,
    float* __restrict__ X, unsigned short* __restrict__ Qb,
    unsigned short* __restrict__ KB4, unsigned short* __restrict__ VB5,
    unsigned short* __restrict__ W1B, unsigned short* __restrict__ W2B) {
  int gid = blockIdx.x * 256 + threadIdx.x;
  int gsz = gridDim.x * 256;
  const int NW = NLAYER * FFD * 32;
  for (int i = gid; i < NW; i += gsz) {
    W1B[i] = f2b(ff1_w[i]);
    W2B[i] = f2b(ff2_w[i]);
  }
  for (int i = gid; i < (QROWS - LL) * 32; i += gsz)
    Qb[(size_t)LL * 32 + i] = 0;                    // query pad rows
  for (int i = gid; i < 8 * (KPAD - LL) * 4; i += gsz) {
    int hh = i / ((KPAD - LL) * 4);
    int rem = i % ((KPAD - LL) * 4);
    KB4[((size_t)hh * KPAD + LL) * 4 + rem] = 0;    // K pad rows
  }
  for (int i = gid; i < 8 * 5 * KPAD; i += gsz) {
    int col = i % KPAD;
    int dd = (i / KPAD) % 5;
    if (dd == 4) {
      int key = (col & ~31) + ((col & 1) << 4) + ((col & 31) >> 1);
      VB5[i] = (key <= 4096) ? 0x3F80 : 0;          // validity row
    } else if (col > 4096) {
      VB5[i] = 0;                                   // pad-key V entries
    }
  }
  // embed + layer-0 qkv: wave items, 2 rows each
  int wave = threadIdx.x >> 6, lane = threadIdx.x & 63;
  int r = lane >> 5, ch = lane & 31;
  unsigned wgid = blockIdx.x * 4 + wave;
  for (unsigned it = wgid; it < 2049; it += gridDim.x * 4) {
    int row = it * 2 + r;
    bool ok = row < LL;
    float val = 0.f;
    if (ok) {
      if (row == 0) {
        val = -1.0f;
      } else {
        int s = row - 1;
        float ts = data[s * 3 + 0];
        float f0 = data[s * 3 + 1];
        float f1 = data[s * 3 + 2];
        float lin = f0 * lin_w[ch * 2 + 0] + f1 * lin_w[ch * 2 + 1] + lin_b[ch];
        lin = fmaxf(lin, 0.0f);
        int tsi = (int)(ts / 100.0f);
        int j = ch >> 1;
        float aj = (float)(2 * j) * (float)(-0.28782313662425575);
        float divj = (float)exp((double)aj);
        float ang = (float)tsi * divj;
        float pe = (ch & 1) ? cosf(ang) : sinf(ang);
        val = lin + pe;
      }
      X[(size_t)row * HDIM + ch] = val;
    }
    qkv_wave(val, row, ok, lane, qkv_w, qkv_b, Qb, KB4, VB5);
  }
}

// ---- attention, swapped-operand MFMA: NO LDS, no transpose (r11 body) ------
__global__ __launch_bounds__(256, 4) void k_attn(
    const unsigned short* __restrict__ Qb, const unsigned short* __restrict__ KB4,
    const unsigned short* __restrict__ VB5, float* __restrict__ LP,
    float4* __restrict__ AP4) {
  int tid = threadIdx.x;
  int wave = tid >> 6, lane = tid & 63;
  int l16 = lane & 15, quad = lane >> 4;
  int h = blockIdx.y, c = blockIdx.z;
  int qs = blockIdx.x * 4 + wave;
  if (qs >= 65) return;                  // wave-uniform exit, no barriers used
  int q0 = qs * 64;
  int kb0 = c * 256;
  int nkb = (c == NCHUNK - 1) ? 9 : 8;

  const unsigned short* KBh = KB4 + (size_t)h * KPAD * 4;
  const unsigned short* VBh = VB5 + (size_t)h * 5 * KPAD;
  const bool kl = (quad == (h & 3));    // carrying quad for K=16 contraction
  const bool vl = (l16 < 5);            // only V rows 0..4 are nonzero
  const int qcol0 = (h >> 2) * 16 + quad * 4;   // Q columns for this quad

  bf16x4 aq[4];                          // Q tiles: B-operand (row = l16 = q)
#pragma unroll
  for (int t = 0; t < 4; ++t)
    aq[t] = *(const bf16x4*)&Qb[(size_t)(q0 + t * 16 + l16) * 32 + qcol0];

  const bf16x4 zb4 = {0, 0, 0, 0};
  const bf16x8 zb8 = {0, 0, 0, 0, 0, 0, 0, 0};
  f32x4 acc0[4], acc1[4];
#pragma unroll
  for (int t = 0; t < 4; ++t) {
    acc0[t] = (f32x4){0.f, 0.f, 0.f, 0.f};
    acc1[t] = (f32x4){0.f, 0.f, 0.f, 0.f};
  }

  auto step = [&](int k0, f32x4* acc) {
    bf16x4 bk0 = kl ? *(const bf16x4*)&KBh[(size_t)(k0 + l16) * 4] : zb4;
    bf16x4 bk1 = kl ? *(const bf16x4*)&KBh[(size_t)(k0 + 16 + l16) * 4] : zb4;
    bf16x8 bv = vl ? *(const bf16x8*)&VBh[(size_t)l16 * KPAD + k0 + quad * 8]
                   : zb8;
    f32x4 z = {0.f, 0.f, 0.f, 0.f};
    unsigned pf[4][4];                   // packed P fragments (bf16x8 each)
#pragma unroll
    for (int t = 0; t < 4; ++t) {
      f32x4 s0 = mfma_qk(bk0, aq[t], z);
      f32x4 s1 = mfma_qk(bk1, aq[t], z);
#pragma unroll
      for (int reg = 0; reg < 4; ++reg)
        pf[t][reg] = pk_bf16(EXP2(s0[reg]), EXP2(s1[reg]));
    }
#pragma unroll
    for (int t = 0; t < 4; ++t) {
      bf16x8 pb = *(const bf16x8*)&pf[t][0];
      acc[t] = __builtin_amdgcn_mfma_f32_16x16x32_bf16(bv, pb, acc[t], 0, 0, 0);
    }
  };

  int kb = 0;
  for (; kb + 2 <= nkb; kb += 2) {
    step(kb0 + kb * 32, acc0);
    step(kb0 + (kb + 1) * 32, acc1);
  }
  if (kb < nkb) step(kb0 + kb * 32, acc0);

  // Output: lane holds O^T rows d=quad*4+reg for q=l16 of each tile.
#pragma unroll
  for (int t = 0; t < 4; ++t) {
    f32x4 a = acc0[t] + acc1[t];
    int q = q0 + t * 16 + l16;
    if (q < LL) {
      if (quad == 0) {
        AP4[((size_t)c * LL + q) * 8 + h] = make_float4(a[0], a[1], a[2], a[3]);
      } else if (quad == 1) {
        LP[((size_t)c * LL + q) * 8 + h] = a[0];
      }
    }
  }
}

// ---- fused per-16-row block: oproj+LN1 -> full FFN -> LN2 -> next qkv ------
// grid (257) x 512 threads (8 waves). Wave w owns the 256-wide f-slice.
__global__ __launch_bounds__(512, 4) void k_ffnF(const float* __restrict__ LP,
    const float* __restrict__ APf, float* __restrict__ X,
    const float* __restrict__ ow, const float* __restrict__ ob,
    const float* __restrict__ g1, const float* __restrict__ b1ln,
    const unsigned short* __restrict__ w1b, const float* __restrict__ fb1,
    const unsigned short* __restrict__ w2b, const float* __restrict__ fb2,
    const float* __restrict__ g2, const float* __restrict__ b2ln,
    const float* __restrict__ qw, const float* __restrict__ qb,
    unsigned short* __restrict__ Qb, unsigned short* __restrict__ KB4,
    unsigned short* __restrict__ VB5) {
  __shared__ unsigned short Xa[RB2][32];      // bf16 LN1 out (GEMM1 A-tile)
  __shared__ float Y1[RB2][32];               // fp32 LN1 out (FFN residual)
  __shared__ unsigned short Fsb[8][16 * 136]; // per-wave transpose buffers
  __shared__ float Pr[8][RB2 * 33];           // per-wave GEMM2 partials
  int tid = threadIdx.x;
  int wave = tid >> 6, lane = tid & 63;
  int l16 = lane & 15, quad = lane >> 4;
  int r = lane >> 5, ch = lane & 31;
  int r0 = blockIdx.x * RB2;

  // Phase A: split-K combine + o-proj + residual + LN1 (2 rows per wave)
  {
    int rl = wave * 2 + r;
    int row = r0 + rl;
    bool ok = row < LL;
    int hh = ch >> 2;
    float L = 0.f, A = 0.f;
    if (ok) {
#pragma unroll
      for (int c = 0; c < NCHUNK; ++c) {
        A += APf[((size_t)c * LL + row) * 32 + ch];
        L += LP[((size_t)c * LL + row) * 8 + hh];
      }
    }
    float os = ok ? A / L : 0.f;
    float acc = 0.f;
    const float4* owr = (const float4*)(ow + (size_t)ch * 32);
#pragma unroll
    for (int k8 = 0; k8 < 8; ++k8) {
      float4 wv = owr[k8];
      acc = fmaf(__shfl(os, (lane & 32) + 4 * k8 + 0, 64), wv.x, acc);
      acc = fmaf(__shfl(os, (lane & 32) + 4 * k8 + 1, 64), wv.y, acc);
      acc = fmaf(__shfl(os, (lane & 32) + 4 * k8 + 2, 64), wv.z, acc);
      acc = fmaf(__shfl(os, (lane & 32) + 4 * k8 + 3, 64), wv.w, acc);
    }
    float val = ok ? (X[(size_t)row * HDIM + ch] + acc + ob[ch]) : 0.f;
    float mean = val;
#pragma unroll
    for (int off = 16; off > 0; off >>= 1) mean += __shfl_xor(mean, off, 32);
    mean *= (1.f / 32.f);
    float d2 = val - mean;
    float var = d2 * d2;
#pragma unroll
    for (int off = 16; off > 0; off >>= 1) var += __shfl_xor(var, off, 32);
    var *= (1.f / 32.f);
    float y = d2 / sqrtf(var + EPSLN) * g1[ch] + b1ln[ch];
    Y1[rl][ch] = y;
    Xa[rl][ch] = ok ? f2b(y) : 0;
  }
  __syncthreads();

  // Phase B: FFN over this wave's 256-wide f-slice (wave-private transpose)
  bf16x8 a1 = *(const bf16x8*)&Xa[l16][quad * 8];
  f32x4 acc2[2] = {{0.f, 0.f, 0.f, 0.f}, {0.f, 0.f, 0.f, 0.f}};
  int fs0 = wave * 256;
#pragma unroll
  for (int sg = 0; sg < 2; ++sg) {
    int f0 = fs0 + sg * 128;
    f32x4 c1[8];
#pragma unroll
    for (int t = 0; t < 8; ++t) {
      bf16x8 b =
          *(const bf16x8*)&w1b[(size_t)(f0 + t * 16 + l16) * 32 + quad * 8];
      f32x4 z = {0.f, 0.f, 0.f, 0.f};
      c1[t] = __builtin_amdgcn_mfma_f32_16x16x32_bf16(a1, b, z, 0, 0, 0);
    }
#pragma unroll
    for (int t = 0; t < 8; ++t) {
      float bb = fb1[f0 + t * 16 + l16];
#pragma unroll
      for (int reg = 0; reg < 4; ++reg) {
        float v = fmaxf(c1[t][reg] + bb, 0.f);
        Fsb[wave][(quad * 4 + reg) * 136 + t * 16 + l16] = f2b(v);
      }
    }
    // Fsb is wave-private; in-order per-wave DS -> no barrier
#pragma unroll
    for (int kt = 0; kt < 4; ++kt) {
      bf16x8 a2 = *(const bf16x8*)&Fsb[wave][l16 * 136 + kt * 32 + quad * 8];
#pragma unroll
      for (int u = 0; u < 2; ++u) {
        bf16x8 b = *(const bf16x8*)&w2b[(size_t)(u * 16 + l16) * FFD + f0 +
                                        kt * 32 + quad * 8];
        acc2[u] =
            __builtin_amdgcn_mfma_f32_16x16x32_bf16(a2, b, acc2[u], 0, 0, 0);
      }
    }
  }
#pragma unroll
  for (int u = 0; u < 2; ++u)
#pragma unroll
    for (int reg = 0; reg < 4; ++reg)
      Pr[wave][(quad * 4 + reg) * 33 + u * 16 + l16] = acc2[u][reg];
  __syncthreads();

  // Phase C: reduce 8 wave partials + residual + LN2 + next layer's qkv
  {
    int rl = wave * 2 + r;
    int row = r0 + rl;
    bool ok = row < LL;
    float s = 0.f;
#pragma unroll
    for (int w = 0; w < 8; ++w) s += Pr[w][rl * 33 + ch];
    float val = ok ? (Y1[rl][ch] + s + fb2[ch]) : 0.f;
    float mean = val;
#pragma unroll
    for (int off = 16; off > 0; off >>= 1) mean += __shfl_xor(mean, off, 32);
    mean *= (1.f / 32.f);
    float d2 = val - mean;
    float var = d2 * d2;
#pragma unroll
    for (int off = 16; off > 0; off >>= 1) var += __shfl_xor(var, off, 32);
    var *= (1.f / 32.f);
    float y = d2 / sqrtf(var + EPSLN) * g2[ch] + b2ln[ch];
    if (ok) X[(size_t)row * HDIM + ch] = y;
    qkv_wave(y, row, ok, lane, qw, qb, Qb, KB4, VB5);
  }
}

// ---- last layer, stage B: oproj+LN1 (redundant) + 64-wide f-slice GEMV -----
// grid (LB=32) x 256. Warp 0 combines row-0 split-K partials + oproj + LN1
// (tiny, redundant per block); block b then computes f in [b*64, b*64+64)
// with bf16 weights (8 KB/block; 256 KB spread over 32 blocks) -> partial.
__global__ __launch_bounds__(256) void k_lastB(const float* __restrict__ LP,
    const float* __restrict__ APf, const float* __restrict__ X,
    const float* __restrict__ ow, const float* __restrict__ ob,
    const float* __restrict__ g1, const float* __restrict__ b1ln,
    const unsigned short* __restrict__ w1b, const float* __restrict__ fb1,
    const unsigned short* __restrict__ w2b, float* __restrict__ y1_ws,
    float* __restrict__ part) {
  __shared__ float y1_sh[32];
  __shared__ float f_sh[64];
  __shared__ float red[8][32];
  int tid = threadIdx.x;
  int b = blockIdx.x;

  if (tid < 32) {
    int ch = tid, hh = ch >> 2;
    float A = 0.f, L = 0.f;
#pragma unroll
    for (int c = 0; c < NCHUNK; ++c) {
      A += APf[((size_t)c * LL) * 32 + ch];
      L += LP[((size_t)c * LL) * 8 + hh];
    }
    float os = A / L;
    float acc = 0.f;
#pragma unroll
    for (int k = 0; k < 32; ++k)
      acc = fmaf(__shfl(os, k, 32), ow[ch * 32 + k], acc);
    float val = X[ch] + acc + ob[ch];
    float mean = val;
#pragma unroll
    for (int off = 16; off > 0; off >>= 1) mean += __shfl_xor(mean, off, 32);
    mean *= (1.f / 32.f);
    float d2 = val - mean;
    float var = d2 * d2;
#pragma unroll
    for (int off = 16; off > 0; off >>= 1) var += __shfl_xor(var, off, 32);
    var *= (1.f / 32.f);
    float y = d2 / sqrtf(var + EPSLN) * g1[ch] + b1ln[ch];
    y1_sh[ch] = y;
    if (b == 0) y1_ws[ch] = y;
  }
  __syncthreads();

  // GEMV1: threads 0..63 each compute one f value of this block's slice
  if (tid < 64) {
    int i = b * 64 + tid;
    const unsigned short* wr = w1b + (size_t)i * 32;
    float acc = fb1[i];
#pragma unroll
    for (int j = 0; j < 32; ++j) acc = fmaf(y1_sh[j], b2f(wr[j]), acc);
    f_sh[tid] = fmaxf(acc, 0.f);
  }
  __syncthreads();

  // GEMV2 partial: ch = tid&31, seg = tid>>5 covers 8 f each
  {
    int ch = tid & 31, seg = tid >> 5;
    float acc = 0.f;
    const unsigned short* wr = w2b + (size_t)ch * FFD + b * 64 + seg * 8;
#pragma unroll
    for (int j = 0; j < 8; ++j) acc = fmaf(f_sh[seg * 8 + j], b2f(wr[j]), acc);
    red[seg][ch] = acc;
  }
  __syncthreads();
  if (tid < 32) {
    float s = 0.f;
#pragma unroll
    for (int sg = 0; sg < 8; ++sg) s += red[sg][tid];
    part[b * 32 + tid] = s;
  }
}

// ---- last layer, stage C: ordered combine + residual + LN2 + classifier ----
__global__ __launch_bounds__(64) void k_lastC(const float* __restrict__ y1_ws,
    const float* __restrict__ part, const float* __restrict__ fb2,
    const float* __restrict__ g2, const float* __restrict__ b2ln,
    const float* __restrict__ cw, const float* __restrict__ cb,
    float* __restrict__ out) {
  int tid = threadIdx.x;
  if (tid >= 32) return;
  int ch = tid;
  float s = 0.f;
#pragma unroll 4
  for (int b = 0; b < LB; ++b) s += part[b * 32 + ch];
  float val = y1_ws[ch] + s + fb2[ch];
  float mean = val;
#pragma unroll
  for (int off = 16; off > 0; off >>= 1) mean += __shfl_xor(mean, off, 32);
  mean *= (1.f / 32.f);
  float d2 = val - mean;
  float var = d2 * d2;
#pragma unroll
  for (int off = 16; off > 0; off >>= 1) var += __shfl_xor(var, off, 32);
  var *= (1.f / 32.f);
  float y = d2 / sqrtf(var + EPSLN) * g2[ch] + b2ln[ch];
  float t = y * cw[ch];
#pragma unroll
  for (int off = 16; off > 0; off >>= 1) t += __shfl_xor(t, off, 32);
  if (ch == 0) out[0] = 1.f / (1.f + expf(-(t + cb[0])));
}

extern "C" void kernel_launch(void* const* d_in, const int* in_sizes, int n_in,
                              void* d_out, int out_size, void* d_ws,
                              size_t ws_size, hipStream_t stream) {
  const float* data  = (const float*)d_in[0];
  const float* lin_w = (const float*)d_in[1];
  const float* lin_b = (const float*)d_in[2];
  const float* qkv_w = (const float*)d_in[3];
  const float* qkv_b = (const float*)d_in[4];
  const float* out_w = (const float*)d_in[5];
  const float* out_b = (const float*)d_in[6];
  const float* ln1_g = (const float*)d_in[7];
  const float* ln1_b = (const float*)d_in[8];
  const float* ff1_w = (const float*)d_in[9];
  const float* ff1_b = (const float*)d_in[10];
  const float* ff2_w = (const float*)d_in[11];
  const float* ff2_b = (const float*)d_in[12];
  const float* ln2_g = (const float*)d_in[13];
  const float* ln2_b = (const float*)d_in[14];
  const float* cls_w = (const float*)d_in[15];
  const float* cls_b = (const float*)d_in[16];

  char* wsb = (char*)d_ws;
  float* X = (float*)wsb;                               // LL*32 fp32
  unsigned short* Qb  = (unsigned short*)(X + (size_t)LL * 32);
  unsigned short* KB4 = Qb + (size_t)QROWS * 32;        // 8*KPAD*4
  unsigned short* VB5 = KB4 + (size_t)8 * KPAD * 4;     // 8*5*KPAD
  unsigned short* W1B = VB5 + (size_t)8 * 5 * KPAD;     // NL*FFD*32
  unsigned short* W2B = W1B + (size_t)NLAYER * FFD * 32;
  float4* AP = (float4*)(((size_t)(W2B + (size_t)NLAYER * FFD * 32) + 15) &
                         ~(size_t)15);                  // NCHUNK*LL*8 float4
  float* LP = (float*)(AP + (size_t)NCHUNK * LL * 8);   // NCHUNK*LL*8 floats
  float* Y1W = LP + (size_t)NCHUNK * LL * 8;            // 32 floats
  float* PART = Y1W + 32;                               // LB*32 floats

  k_init<<<1024, 256, 0, stream>>>(data, lin_w, lin_b, qkv_w, qkv_b,
                                   ff1_w, ff2_w, X, Qb, KB4, VB5, W1B, W2B);
  for (int l = 0; l < NLAYER - 1; ++l) {
    k_attn<<<dim3(17, 8, NCHUNK), 256, 0, stream>>>(Qb, KB4, VB5, LP, AP);
    // ffnF always computes the NEXT layer's qkv (layer l+1; l+1 <= 5)
    const float* qw = qkv_w + (size_t)(l + 1) * 96 * 32;
    const float* qb = qkv_b + (size_t)(l + 1) * 96;
    k_ffnF<<<(LL + RB2 - 1) / RB2, 512, 0, stream>>>(
        LP, (const float*)AP, X,
        out_w + (size_t)l * 32 * 32, out_b + (size_t)l * 32,
        ln1_g + (size_t)l * 32, ln1_b + (size_t)l * 32,
        W1B + (size_t)l * FFD * 32, ff1_b + (size_t)l * FFD,
        W2B + (size_t)l * FFD * 32, ff2_b + (size_t)l * 32,
        ln2_g + (size_t)l * 32, ln2_b + (size_t)l * 32,
        qw, qb, Qb, KB4, VB5);
  }
  // layer 5: only CLS (row 0) is consumed -> attn restricted to q-group 0,
  // then parallel small-GEMV stages.
  {
    const int l = NLAYER - 1;
    k_attn<<<dim3(1, 8, NCHUNK), 256, 0, stream>>>(Qb, KB4, VB5, LP, AP);
    k_lastB<<<LB, 256, 0, stream>>>(
        LP, (const float*)AP, X,
        out_w + (size_t)l * 32 * 32, out_b + (size_t)l * 32,
        ln1_g + (size_t)l * 32, ln1_b + (size_t)l * 32,
        W1B + (size_t)l * FFD * 32, ff1_b + (size_t)l * FFD,
        W2B + (size_t)l * FFD * 32, Y1W, PART);
    k_lastC<<<1, 64, 0, stream>>>(Y1W, PART, ff2_b + (size_t)l * 32,
                                  ln2_g + (size_t)l * 32,
                                  ln2_b + (size_t)l * 32,
                                  cls_w, cls_b, (float*)d_out);
  }
}